// Round 4
// baseline (15702.100 us; speedup 1.0000x reference)
//
#include <hip/hip_runtime.h>
#include <hip/hip_bf16.h>

// Problem: BATCH=128, SEQ=1024, DIN=512, HID=512 (all fp32)
// out = final hidden state (128, 512) of h_t = tanh(x_t@Wx + h_{t-1}@Wh + b)
//
// R5 (from R4): R4 fixed the publish write-amplification (WRITE_SIZE 2.1GB ->
// 266MB) but time was unchanged -> writes were not the critical path.
// VGPR_Count=56 proved w2[32] (64 regs of Wh) was NOT register-resident:
// the compiler sank the Wh loads into the step loop, and the per-step
// agent-scope acquire (spin poll) invalidates the XCD L2 (non-coherent
// across XCDs) -> Wh re-fetched at LLC latency inside the MAC every step.
// R5 changes:
//  1. Pin w2 in VGPRs via empty inline asm ("+v") -> rematerialization
//     impossible; MAC becomes pure LDS+register work.
//  2. Spin with RELAXED polls + ONE acquire fence after the barrier
//     (instead of an invalidating acquire per poll).

#define BATCH 128
#define SEQ   1024
#define DIN   512
#define HID   512

#define NG  16   // batch groups
#define NC  8    // col groups
#define RPB 8    // rows per block
#define CPB 64   // cols per block

typedef float v2f __attribute__((ext_vector_type(2)));

// ---------------------------------------------------------------------------
// Kernel 1: xp[s][b][j] = sum_d x[b][s][d] * Wx[d][j] + bias[j]   (unchanged)
// ---------------------------------------------------------------------------
__global__ __launch_bounds__(256) void xp_gemm(
    const float* __restrict__ x, const float* __restrict__ Wx,
    const float* __restrict__ bias, float* __restrict__ xp,
    int s0)
{
    __shared__ __align__(16) float As[16][64 + 4];
    __shared__ __align__(16) float Bs[16][64];

    const int tid = threadIdx.x;
    const int tx = tid & 15;
    const int ty = tid >> 4;
    const int rowBase = blockIdx.x * 64;
    const int colBase = blockIdx.y * 64;

    const int a_r  = tid >> 2;
    const int a_k4 = (tid & 3) * 4;
    const int rr   = rowBase + a_r;
    const int s    = s0 + (rr >> 7);
    const int bb   = rr & 127;
    const float* a_row = x + ((size_t)bb * SEQ + s) * DIN;

    const int b_kk = tid >> 4;
    const int b_j4 = (tid & 15) * 4;

    v2f C[4][2] = {};

    for (int k0 = 0; k0 < DIN; k0 += 16) {
        float4 av = *reinterpret_cast<const float4*>(a_row + k0 + a_k4);
        As[a_k4 + 0][a_r] = av.x;
        As[a_k4 + 1][a_r] = av.y;
        As[a_k4 + 2][a_r] = av.z;
        As[a_k4 + 3][a_r] = av.w;
        float4 bv = *reinterpret_cast<const float4*>(Wx + (size_t)(k0 + b_kk) * HID + colBase + b_j4);
        *reinterpret_cast<float4*>(&Bs[b_kk][b_j4]) = bv;
        __syncthreads();

        #pragma unroll
        for (int kk = 0; kk < 16; ++kk) {
            float4 a4 = *reinterpret_cast<const float4*>(&As[kk][ty * 4]);
            float4 b4 = *reinterpret_cast<const float4*>(&Bs[kk][tx * 4]);
            v2f b01 = {b4.x, b4.y};
            v2f b23 = {b4.z, b4.w};
            float a[4] = {a4.x, a4.y, a4.z, a4.w};
            #pragma unroll
            for (int i = 0; i < 4; ++i) {
                C[i][0] += b01 * a[i];
                C[i][1] += b23 * a[i];
            }
        }
        __syncthreads();
    }

    float4 bias4 = *reinterpret_cast<const float4*>(bias + colBase + tx * 4);
    #pragma unroll
    for (int i = 0; i < 4; ++i) {
        int orow = rowBase + ty * 4 + i;
        float4 o;
        o.x = C[i][0].x + bias4.x;
        o.y = C[i][0].y + bias4.y;
        o.z = C[i][1].x + bias4.z;
        o.w = C[i][1].y + bias4.w;
        *reinterpret_cast<float4*>(xp + (size_t)orow * HID + colBase + tx * 4) = o;
    }
}

// ---------------------------------------------------------------------------
// Flag init (flags live in re-poisoned ws -> must be zeroed every call)
// ---------------------------------------------------------------------------
__global__ void init_flags(unsigned int* flags)
{
    flags[threadIdx.x] = 0u;
}

// ---------------------------------------------------------------------------
// Kernel 2: column-split recurrence.
//   Block (cb, bb): rows [8bb, 8bb+8), cols [64cb, 64cb+64).
//
//   MAC mapping:    tid = kg*32 + c2   (kg in [0,16): 32 k-rows; c2: col pair)
//   Reduce mapping: tid = rr*64 + cc   (rr: row, cc: col)
//
//   hxT global exchange layout: [buf][bb][r*HID + k], k = cb*64+cc.
//   Publish: lane-coalesced (consecutive cc -> consecutive 4B).
//   Pull: identity copy into hT (hT semantic = [r][k]).
//   MAC: reads hT[r*512 + kg*32 + 4q ..+3] as float4 -> address uniform
//   across each 32-lane group (LDS broadcast, conflict-free).
// ---------------------------------------------------------------------------
__global__ __launch_bounds__(512, 1) void recur_kernel(
    const float* __restrict__ xp,       // chunk base: xp[s-s0][b][j]
    const float* __restrict__ Wh,
    float* __restrict__ out,
    unsigned int* __restrict__ flags,   // [NG*NC]
    unsigned int* __restrict__ hxT,     // [2][NG][RPB*HID]
    int s0, int steps)
{
    const int bb = blockIdx.x % NG;
    const int cb = blockIdx.x / NG;

    const int tid = threadIdx.x;
    const int c2 = tid & 31;     // col pair within slice
    const int kg = tid >> 5;     // k-group (32 rows each)
    const int rr = tid >> 6;     // reduce: row 0..7
    const int cc = tid & 63;     // reduce: col 0..63

    __shared__ __align__(16) float hT[RPB * HID];        // [r][k]  16 KB
    __shared__ __align__(16) float part[NG * RPB * CPB]; // [kg][r][c] 32 KB

    // ---- preload Wh slice into registers: w2[kk] = Wh[32kg+kk][64cb+2c2 ..+1]
    v2f w2[32];
    {
        const float* wbase = Wh + (size_t)(kg * 32) * HID + 64 * cb + 2 * c2;
        #pragma unroll
        for (int kk = 0; kk < 32; ++kk)
            w2[kk] = *reinterpret_cast<const v2f*>(wbase + (size_t)kk * HID);
    }
    // Pin the slice into VGPRs: opaque asm makes rematerialization impossible,
    // so the per-step MAC touches no global memory (cache invalidations from
    // the acquire fence below cannot evict registers).
    #pragma unroll
    for (int kk = 0; kk < 32; ++kk)
        asm volatile("" : "+v"(w2[kk]));

    const int kbase = kg * 32;
    const int send = s0 + steps;
    for (int s = s0; s < send; ++s) {
        // prefetch xp for this step (consumed at reduce time)
        float xpv = xp[((size_t)(s - s0) * BATCH + (RPB * bb + rr)) * HID + CPB * cb + cc];

        // ---- obtain h_s into hT  (layout [r][k])
        if (s == 0) {
            #pragma unroll
            for (int i = 0; i < 8; ++i)
                hT[i * 512 + tid] = 0.0f;
        } else {
            if (tid < NC) {
                const unsigned target = (unsigned)s;
                // RELAXED polls: no per-iteration cache maintenance.
                while (__hip_atomic_load(&flags[bb * NC + tid],
                                         __ATOMIC_RELAXED,
                                         __HIP_MEMORY_SCOPE_AGENT) < target) { }
            }
            __syncthreads();
            // One acquire per step: synchronizes-with the producers' release
            // flag stores observed by the polls above (fence-based sync).
            __builtin_amdgcn_fence(__ATOMIC_ACQUIRE, "agent");
            const unsigned int* src = hxT + ((size_t)(s & 1) * NG + bb) * (RPB * HID);
            #pragma unroll
            for (int i = 0; i < 8; ++i) {
                int idx = i * 512 + tid;
                unsigned int u = __hip_atomic_load(&src[idx], __ATOMIC_RELAXED,
                                                   __HIP_MEMORY_SCOPE_AGENT);
                hT[idx] = __uint_as_float(u);
            }
        }
        __syncthreads();

        // ---- MAC phase: acc[r] (v2f over col pair) over 32 k-rows
        // hT is [r][k]; per (q,r) read float4 h[r][kbase+4q..+3] (broadcast
        // within the 32-lane group) and FMA against 4 resident w2 pairs.
        v2f acc[8] = {};
        #pragma unroll
        for (int q = 0; q < 8; ++q) {
            v2f wa = w2[q * 4 + 0];
            v2f wb = w2[q * 4 + 1];
            v2f wc = w2[q * 4 + 2];
            v2f wd = w2[q * 4 + 3];
            #pragma unroll
            for (int r = 0; r < 8; ++r) {
                float4 hv = *reinterpret_cast<const float4*>(&hT[r * HID + kbase + q * 4]);
                acc[r] += wa * hv.x;
                acc[r] += wb * hv.y;
                acc[r] += wc * hv.z;
                acc[r] += wd * hv.w;
            }
        }

        // ---- write partials: part[kg][r][c]
        #pragma unroll
        for (int r = 0; r < 8; ++r)
            *reinterpret_cast<v2f*>(&part[(kg * RPB + r) * CPB + 2 * c2]) = acc[r];
        __syncthreads();

        // ---- reduce across 16 k-groups, add xp, tanh
        float sum = xpv;
        #pragma unroll
        for (int g = 0; g < NG; ++g)
            sum += part[(g * RPB + rr) * CPB + cc];
        float hn = tanhf(sum);

        // ---- publish h_{s+1} slice, coalesced (agent scope -> coherence point)
        unsigned int* dst = hxT + ((size_t)((s + 1) & 1) * NG + bb) * (RPB * HID);
        __hip_atomic_store(&dst[rr * HID + CPB * cb + cc], __float_as_uint(hn),
                           __ATOMIC_RELAXED, __HIP_MEMORY_SCOPE_AGENT);
        if (s == SEQ - 1)
            out[(size_t)(RPB * bb + rr) * HID + CPB * cb + cc] = hn;

        // __syncthreads drains vmcnt before barrier -> all 512 threads' stores
        // are at the coherence point before the flag is released.
        __syncthreads();
        if (tid == 0)
            __hip_atomic_store(&flags[bb * NC + cb], (unsigned)(s + 1),
                               __ATOMIC_RELEASE, __HIP_MEMORY_SCOPE_AGENT);
    }
}

// ---------------------------------------------------------------------------
// Fallback (ws too small): fully fused, zero workspace.
// ---------------------------------------------------------------------------
__global__ __launch_bounds__(512) void fused_kernel(
    const float* __restrict__ x, const float* __restrict__ Wx,
    const float* __restrict__ Wh, const float* __restrict__ bias,
    float* __restrict__ out)
{
    __shared__ __align__(16) float h0[HID];
    __shared__ __align__(16) float h1[HID];
    __shared__ __align__(16) float x0[DIN];
    __shared__ __align__(16) float x1[DIN];

    const int j = threadIdx.x;
    const int b0 = blockIdx.x * 2;
    const int b1 = b0 + 1;

    h0[j] = 0.0f;
    h1[j] = 0.0f;
    __syncthreads();

    const float4* h04 = reinterpret_cast<const float4*>(h0);
    const float4* h14 = reinterpret_cast<const float4*>(h1);
    const float4* x04 = reinterpret_cast<const float4*>(x0);
    const float4* x14 = reinterpret_cast<const float4*>(x1);

    for (int s = 0; s < SEQ; ++s) {
        x0[j] = x[((size_t)b0 * SEQ + s) * DIN + j];
        x1[j] = x[((size_t)b1 * SEQ + s) * DIN + j];
        __syncthreads();

        float acc0 = bias[j];
        float acc1 = bias[j];
        const float* wx = Wx + j;
        const float* wh = Wh + j;
        #pragma unroll 2
        for (int k4 = 0; k4 < HID / 4; ++k4) {
            float4 hv0 = h04[k4];
            float4 hv1 = h14[k4];
            float4 xv0 = x04[k4];
            float4 xv1 = x14[k4];
            int k = k4 * 4;
            #pragma unroll
            for (int u = 0; u < 4; ++u) {
                float wxv = wx[(size_t)(k + u) * HID];
                float whv = wh[(size_t)(k + u) * HID];
                float he0 = (u == 0) ? hv0.x : (u == 1) ? hv0.y : (u == 2) ? hv0.z : hv0.w;
                float he1 = (u == 0) ? hv1.x : (u == 1) ? hv1.y : (u == 2) ? hv1.z : hv1.w;
                float xe0 = (u == 0) ? xv0.x : (u == 1) ? xv0.y : (u == 2) ? xv0.z : xv0.w;
                float xe1 = (u == 0) ? xv1.x : (u == 1) ? xv1.y : (u == 2) ? xv1.z : xv1.w;
                acc0 += xe0 * wxv + he0 * whv;
                acc1 += xe1 * wxv + he1 * whv;
            }
        }

        float n0 = tanhf(acc0);
        float n1 = tanhf(acc1);
        __syncthreads();
        h0[j] = n0;
        h1[j] = n1;
        __syncthreads();
    }

    out[(size_t)b0 * HID + j] = h0[j];
    out[(size_t)b1 * HID + j] = h1[j];
}

// ---------------------------------------------------------------------------
extern "C" void kernel_launch(void* const* d_in, const int* in_sizes, int n_in,
                              void* d_out, int out_size, void* d_ws, size_t ws_size,
                              hipStream_t stream)
{
    const float* x    = (const float*)d_in[0];  // (128, 1024, 512)
    const float* Wx   = (const float*)d_in[1];  // (512, 512)
    const float* Wh   = (const float*)d_in[2];  // (512, 512)
    const float* bias = (const float*)d_in[3];  // (512,)
    float* out = (float*)d_out;                 // (128, 512)

    const size_t flagsBytes = 4096;                                  // NG*NC*4 padded
    const size_t hxBytes    = 2ull * NG * (HID * RPB) * sizeof(float); // 512 KB
    const size_t stepBytes  = (size_t)BATCH * HID * sizeof(float);     // 256 KB
    const size_t fixed      = flagsBytes + hxBytes;

    size_t xpCapSteps = (ws_size > fixed) ? (ws_size - fixed) / stepBytes : 0;

    if (xpCapSteps >= 1) {
        unsigned int* flags = (unsigned int*)d_ws;
        unsigned int* hxT   = (unsigned int*)((char*)d_ws + flagsBytes);
        float* xp           = (float*)((char*)d_ws + fixed);

        init_flags<<<1, NG * NC, 0, stream>>>(flags);

        int chunk = (int)((xpCapSteps < (size_t)SEQ) ? xpCapSteps : (size_t)SEQ);
        int s0 = 0;
        while (s0 < SEQ) {
            int steps = (SEQ - s0 < chunk) ? (SEQ - s0) : chunk;
            dim3 ggrid((unsigned)(steps * BATCH / 64), HID / 64);
            xp_gemm<<<ggrid, 256, 0, stream>>>(x, Wx, bias, xp, s0);
            recur_kernel<<<NG * NC, 512, 0, stream>>>(xp, Wh, out, flags, hxT,
                                                      s0, steps);
            s0 += steps;
        }
    } else {
        fused_kernel<<<BATCH / 2, HID, 0, stream>>>(x, Wx, Wh, bias, out);
    }
}

// Round 6
// 8983.075 us; speedup vs baseline: 1.7480x; 1.7480x over previous
//
#include <hip/hip_runtime.h>
#include <hip/hip_bf16.h>

// Problem: BATCH=128, SEQ=1024, DIN=512, HID=512 (all fp32)
// out = final hidden state (128, 512) of h_t = tanh(x_t@Wx + h_{t-1}@Wh + b)
//
// R7 = R6 resubmit (round-5 bench was an infra container failure; audit found
// no hang/OOB path) + 4th MFMA product (lo*lo) for accuracy margin.
//
// Design: Wh slice lives in LDS (immune to regalloc AND to the per-step agent
// acquire invalidations that were re-pulling it from LLC each step in R3-R5:
// VGPR_Count=56 proved registers never held it). MAC via split-bf16 MFMA
// (W = W_hi + W_lo, h = h_hi + h_lo; all 4 products -> only ~2^-17
// representation residual vs fp32; recurrence is contractive, fp32 baseline
// absmax was bit-identical 2^-9 across accumulation orders).
// Geometry: NG=8 batch groups (16 rows) x NC=16 col groups (32 cols)
// = 128 blocks x 512 threads (8 waves: 2 col-tiles x 4 k-quarters).
// Sync protocol identical to R4 (acquire polls, proven correct).

#define BATCH 128
#define SEQ   1024
#define DIN   512
#define HID   512

#define NG  8    // batch groups
#define NC  16   // col groups
#define RPB 16   // rows per block
#define CPB 32   // cols per block

typedef float v2f __attribute__((ext_vector_type(2)));
typedef __attribute__((ext_vector_type(8))) short bf16x8;
typedef __attribute__((ext_vector_type(4))) float f32x4;

// ---------------------------------------------------------------------------
// Kernel 1: xp[s][b][j] = sum_d x[b][s][d] * Wx[d][j] + bias[j]   (unchanged)
// ---------------------------------------------------------------------------
__global__ __launch_bounds__(256) void xp_gemm(
    const float* __restrict__ x, const float* __restrict__ Wx,
    const float* __restrict__ bias, float* __restrict__ xp,
    int s0)
{
    __shared__ __align__(16) float As[16][64 + 4];
    __shared__ __align__(16) float Bs[16][64];

    const int tid = threadIdx.x;
    const int tx = tid & 15;
    const int ty = tid >> 4;
    const int rowBase = blockIdx.x * 64;
    const int colBase = blockIdx.y * 64;

    const int a_r  = tid >> 2;
    const int a_k4 = (tid & 3) * 4;
    const int rr   = rowBase + a_r;
    const int s    = s0 + (rr >> 7);
    const int bb   = rr & 127;
    const float* a_row = x + ((size_t)bb * SEQ + s) * DIN;

    const int b_kk = tid >> 4;
    const int b_j4 = (tid & 15) * 4;

    v2f C[4][2] = {};

    for (int k0 = 0; k0 < DIN; k0 += 16) {
        float4 av = *reinterpret_cast<const float4*>(a_row + k0 + a_k4);
        As[a_k4 + 0][a_r] = av.x;
        As[a_k4 + 1][a_r] = av.y;
        As[a_k4 + 2][a_r] = av.z;
        As[a_k4 + 3][a_r] = av.w;
        float4 bv = *reinterpret_cast<const float4*>(Wx + (size_t)(k0 + b_kk) * HID + colBase + b_j4);
        *reinterpret_cast<float4*>(&Bs[b_kk][b_j4]) = bv;
        __syncthreads();

        #pragma unroll
        for (int kk = 0; kk < 16; ++kk) {
            float4 a4 = *reinterpret_cast<const float4*>(&As[kk][ty * 4]);
            float4 b4 = *reinterpret_cast<const float4*>(&Bs[kk][tx * 4]);
            v2f b01 = {b4.x, b4.y};
            v2f b23 = {b4.z, b4.w};
            float a[4] = {a4.x, a4.y, a4.z, a4.w};
            #pragma unroll
            for (int i = 0; i < 4; ++i) {
                C[i][0] += b01 * a[i];
                C[i][1] += b23 * a[i];
            }
        }
        __syncthreads();
    }

    float4 bias4 = *reinterpret_cast<const float4*>(bias + colBase + tx * 4);
    #pragma unroll
    for (int i = 0; i < 4; ++i) {
        int orow = rowBase + ty * 4 + i;
        float4 o;
        o.x = C[i][0].x + bias4.x;
        o.y = C[i][0].y + bias4.y;
        o.z = C[i][1].x + bias4.z;
        o.w = C[i][1].y + bias4.w;
        *reinterpret_cast<float4*>(xp + (size_t)orow * HID + colBase + tx * 4) = o;
    }
}

// ---------------------------------------------------------------------------
__global__ void init_flags(unsigned int* flags)
{
    flags[threadIdx.x] = 0u;
}

// ---------------------------------------------------------------------------
// Kernel 2: column-split recurrence, MFMA split-bf16 edition.
//   Block (cb, bb): rows [16bb, 16bb+16), cols [32cb, 32cb+32).
//   blockIdx = cb*NG + bb (group members share blockIdx&7 -> XCD coset).
//
//   Waves: wv = tid>>6; ct = wv&1 (col 16-tile), kq = wv>>1 (128-k quarter).
//   Each wave: D[16x16] over its k-quarter via 4 k-steps x 4 split products.
//   part[kq][ct][16][16] reduced by thread (rr=tid>>5, cc=tid&31).
//
//   LDS planes (bf16, XOR-swizzled: sidx = row*512 + (k ^ ((row&7)<<3))):
//     h_hi/h_lo  [16][512]  - rebuilt from pulled packed u32 every step
//     wT_hi/wT_lo[32][512]  - Wh slice transposed, built once per dispatch
//
//   hxT exchange: packed u32 (bf16hi<<16 | bf16lo), layout [buf][bb][r*512+k].
// ---------------------------------------------------------------------------
__global__ __launch_bounds__(512) void recur_kernel(
    const float* __restrict__ xp,       // chunk base: xp[s-s0][b][j]
    const float* __restrict__ Wh,
    float* __restrict__ out,
    unsigned int* __restrict__ flags,   // [NG*NC]
    unsigned int* __restrict__ hxT,     // [2][NG][RPB*HID] packed u32
    int s0, int steps)
{
    const int bb = blockIdx.x & 7;
    const int cb = blockIdx.x >> 3;

    const int tid  = threadIdx.x;
    const int lane = tid & 63;
    const int wv   = tid >> 6;
    const int ct   = wv & 1;
    const int kq   = wv >> 1;

    const int rr = tid >> 5;    // reduce: row 0..15
    const int cc = tid & 31;    // reduce: col 0..31

    __shared__ __align__(16) short h_hi[RPB * HID];
    __shared__ __align__(16) short h_lo[RPB * HID];
    __shared__ __align__(16) short wT_hi[CPB * HID];
    __shared__ __align__(16) short wT_lo[CPB * HID];
    __shared__ __align__(16) float part[4][2][16][16];

    // ---- build split-bf16 Wh^T slice in LDS, once per dispatch.
    // thread (cj = tid&31, kk = tid>>5) handles k = i*16+kk for its col cj.
    {
        const int cj = tid & 31;
        const int kk = tid >> 5;
        for (int i = 0; i < 32; ++i) {
            int k = i * 16 + kk;
            float w = Wh[(size_t)k * HID + CPB * cb + cj];
            unsigned int u = __float_as_uint(w);
            short hi = (short)(u >> 16);
            float r = w - __uint_as_float(u & 0xFFFF0000u);
            short lo = (short)(__float_as_uint(r) >> 16);
            int sidx = cj * HID + (k ^ ((cj & 7) << 3));
            wT_hi[sidx] = hi;
            wT_lo[sidx] = lo;
        }
    }

    // MFMA fragment addressing (loop-invariant)
    const int frow = lane & 15;             // A-row / B-col / D-col
    const int fk8  = (lane >> 4) * 8;       // k offset of this lane's 8 elems
    const int xm_a = (frow & 7) << 3;
    const int fcol = ct * 16 + frow;
    const int xm_b = (fcol & 7) << 3;
    const int a_base = frow * HID;
    const int b_base = fcol * HID;

    const int send = s0 + steps;
    for (int s = s0; s < send; ++s) {
        // prefetch xp for this step (consumed at reduce time)
        float xpv = xp[((size_t)(s - s0) * BATCH + (RPB * bb + rr)) * HID + CPB * cb + cc];

        // ---- obtain h_s into the swizzled LDS planes
        if (s == 0) {
            #pragma unroll
            for (int i = 0; i < RPB; ++i) {
                int sidx = i * HID + (tid ^ ((i & 7) << 3));
                h_hi[sidx] = 0;
                h_lo[sidx] = 0;
            }
        } else {
            if (tid < NC) {
                const unsigned target = (unsigned)s;
                while (__hip_atomic_load(&flags[bb * NC + tid],
                                         __ATOMIC_ACQUIRE,
                                         __HIP_MEMORY_SCOPE_AGENT) < target) { }
            }
            __syncthreads();
            const unsigned int* src = hxT + ((size_t)(s & 1) * NG + bb) * (RPB * HID);
            #pragma unroll
            for (int i = 0; i < RPB; ++i) {
                unsigned int u = __hip_atomic_load(&src[i * HID + tid], __ATOMIC_RELAXED,
                                                   __HIP_MEMORY_SCOPE_AGENT);
                int sidx = i * HID + (tid ^ ((i & 7) << 3));
                h_hi[sidx] = (short)(u >> 16);
                h_lo[sidx] = (short)(u & 0xFFFFu);
            }
        }
        __syncthreads();

        // ---- MFMA phase: wave (ct,kq) computes 16x16 over its 128-k quarter
        f32x4 acc = {0.f, 0.f, 0.f, 0.f};
        #pragma unroll
        for (int kt = 0; kt < 4; ++kt) {
            int kb = kq * 128 + kt * 32 + fk8;
            bf16x8 ah = *reinterpret_cast<const bf16x8*>(&h_hi[a_base + (kb ^ xm_a)]);
            bf16x8 al = *reinterpret_cast<const bf16x8*>(&h_lo[a_base + (kb ^ xm_a)]);
            bf16x8 bh = *reinterpret_cast<const bf16x8*>(&wT_hi[b_base + (kb ^ xm_b)]);
            bf16x8 bl = *reinterpret_cast<const bf16x8*>(&wT_lo[b_base + (kb ^ xm_b)]);
            acc = __builtin_amdgcn_mfma_f32_16x16x32_bf16(ah, bh, acc, 0, 0, 0);
            acc = __builtin_amdgcn_mfma_f32_16x16x32_bf16(ah, bl, acc, 0, 0, 0);
            acc = __builtin_amdgcn_mfma_f32_16x16x32_bf16(al, bh, acc, 0, 0, 0);
            acc = __builtin_amdgcn_mfma_f32_16x16x32_bf16(al, bl, acc, 0, 0, 0);
        }

        // ---- store partials: D mapping col=lane&15, row=(lane>>4)*4+j (m89)
        #pragma unroll
        for (int j = 0; j < 4; ++j)
            part[kq][ct][(lane >> 4) * 4 + j][lane & 15] = acc[j];
        __syncthreads();

        // ---- reduce 4 k-quarters, add xp, tanh
        float sum = xpv;
        #pragma unroll
        for (int g = 0; g < 4; ++g)
            sum += part[g][cc >> 4][rr][cc & 15];
        float hn = tanhf(sum);

        // ---- pack split-bf16 and publish (agent scope)
        unsigned int uh = __float_as_uint(hn);
        float rres = hn - __uint_as_float(uh & 0xFFFF0000u);
        unsigned int packed = (uh & 0xFFFF0000u) | (__float_as_uint(rres) >> 16);

        unsigned int* dst = hxT + ((size_t)((s + 1) & 1) * NG + bb) * (RPB * HID);
        __hip_atomic_store(&dst[rr * HID + CPB * cb + cc], packed,
                           __ATOMIC_RELAXED, __HIP_MEMORY_SCOPE_AGENT);
        if (s == SEQ - 1)
            out[(size_t)(RPB * bb + rr) * HID + CPB * cb + cc] = hn;

        // __syncthreads drains vmcnt -> all 512 threads' stores at coherence
        // point before the flag release.
        __syncthreads();
        if (tid == 0)
            __hip_atomic_store(&flags[bb * NC + cb], (unsigned)(s + 1),
                               __ATOMIC_RELEASE, __HIP_MEMORY_SCOPE_AGENT);
    }
}

// ---------------------------------------------------------------------------
// Fallback (ws too small): fully fused, zero workspace.
// ---------------------------------------------------------------------------
__global__ __launch_bounds__(512) void fused_kernel(
    const float* __restrict__ x, const float* __restrict__ Wx,
    const float* __restrict__ Wh, const float* __restrict__ bias,
    float* __restrict__ out)
{
    __shared__ __align__(16) float h0[HID];
    __shared__ __align__(16) float h1[HID];
    __shared__ __align__(16) float x0[DIN];
    __shared__ __align__(16) float x1[DIN];

    const int j = threadIdx.x;
    const int b0 = blockIdx.x * 2;
    const int b1 = b0 + 1;

    h0[j] = 0.0f;
    h1[j] = 0.0f;
    __syncthreads();

    const float4* h04 = reinterpret_cast<const float4*>(h0);
    const float4* h14 = reinterpret_cast<const float4*>(h1);
    const float4* x04 = reinterpret_cast<const float4*>(x0);
    const float4* x14 = reinterpret_cast<const float4*>(x1);

    for (int s = 0; s < SEQ; ++s) {
        x0[j] = x[((size_t)b0 * SEQ + s) * DIN + j];
        x1[j] = x[((size_t)b1 * SEQ + s) * DIN + j];
        __syncthreads();

        float acc0 = bias[j];
        float acc1 = bias[j];
        const float* wx = Wx + j;
        const float* wh = Wh + j;
        #pragma unroll 2
        for (int k4 = 0; k4 < HID / 4; ++k4) {
            float4 hv0 = h04[k4];
            float4 hv1 = h14[k4];
            float4 xv0 = x04[k4];
            float4 xv1 = x14[k4];
            int k = k4 * 4;
            #pragma unroll
            for (int u = 0; u < 4; ++u) {
                float wxv = wx[(size_t)(k + u) * HID];
                float whv = wh[(size_t)(k + u) * HID];
                float he0 = (u == 0) ? hv0.x : (u == 1) ? hv0.y : (u == 2) ? hv0.z : hv0.w;
                float he1 = (u == 0) ? hv1.x : (u == 1) ? hv1.y : (u == 2) ? hv1.z : hv1.w;
                float xe0 = (u == 0) ? xv0.x : (u == 1) ? xv0.y : (u == 2) ? xv0.z : xv0.w;
                float xe1 = (u == 0) ? xv1.x : (u == 1) ? xv1.y : (u == 2) ? xv1.z : xv1.w;
                acc0 += xe0 * wxv + he0 * whv;
                acc1 += xe1 * wxv + he1 * whv;
            }
        }

        float n0 = tanhf(acc0);
        float n1 = tanhf(acc1);
        __syncthreads();
        h0[j] = n0;
        h1[j] = n1;
        __syncthreads();
    }

    out[(size_t)b0 * HID + j] = h0[j];
    out[(size_t)b1 * HID + j] = h1[j];
}

// ---------------------------------------------------------------------------
extern "C" void kernel_launch(void* const* d_in, const int* in_sizes, int n_in,
                              void* d_out, int out_size, void* d_ws, size_t ws_size,
                              hipStream_t stream)
{
    const float* x    = (const float*)d_in[0];  // (128, 1024, 512)
    const float* Wx   = (const float*)d_in[1];  // (512, 512)
    const float* Wh   = (const float*)d_in[2];  // (512, 512)
    const float* bias = (const float*)d_in[3];  // (512,)
    float* out = (float*)d_out;                 // (128, 512)

    const size_t flagsBytes = 4096;                                    // NG*NC*4 padded
    const size_t hxBytes    = 2ull * NG * (HID * RPB) * sizeof(unsigned int); // 512 KB
    const size_t stepBytes  = (size_t)BATCH * HID * sizeof(float);     // 256 KB
    const size_t fixed      = flagsBytes + hxBytes;

    size_t xpCapSteps = (ws_size > fixed) ? (ws_size - fixed) / stepBytes : 0;

    if (xpCapSteps >= 1) {
        unsigned int* flags = (unsigned int*)d_ws;
        unsigned int* hxT   = (unsigned int*)((char*)d_ws + flagsBytes);
        float* xp           = (float*)((char*)d_ws + fixed);

        init_flags<<<1, NG * NC, 0, stream>>>(flags);

        int chunk = (int)((xpCapSteps < (size_t)SEQ) ? xpCapSteps : (size_t)SEQ);
        int s0 = 0;
        while (s0 < SEQ) {
            int steps = (SEQ - s0 < chunk) ? (SEQ - s0) : chunk;
            dim3 ggrid((unsigned)(steps * BATCH / 64), HID / 64);
            xp_gemm<<<ggrid, 256, 0, stream>>>(x, Wx, bias, xp, s0);
            recur_kernel<<<NG * NC, 512, 0, stream>>>(xp, Wh, out, flags, hxT,
                                                      s0, steps);
            s0 += steps;
        }
    } else {
        fused_kernel<<<BATCH / 2, HID, 0, stream>>>(x, Wx, Wh, bias, out);
    }
}

// Round 7
// 5719.051 us; speedup vs baseline: 2.7456x; 1.5707x over previous
//
#include <hip/hip_runtime.h>
#include <hip/hip_bf16.h>

// Problem: BATCH=128, SEQ=1024, DIN=512, HID=512 (all fp32)
// out = final hidden state (128, 512) of h_t = tanh(x_t@Wx + h_{t-1}@Wh + b)
//
// R8 (from R7): R7 proved compute is ~3% of the step (MfmaUtil 1.4%,
// VALUBusy 1.5%) -- the 7.7us/step is the exchange protocol: publish
// vmcnt-drain at __syncthreads (stores write through to HBM: WRITE_SIZE ==
// published bytes), flag release round-trip, acquire-poll invalidations,
// 4 barriers/step. R8 replaces flags+release/acquire with a SELF-TAGGED
// u64 exchange: each element is one relaxed agent-scope 8B atomic
// {tag=step (hi32), packed split-bf16 h (lo32)}. Tag travels with data ->
// no ordering, no drains, no flag, relaxed polls, 2 barriers/step.
// Ping-pong buffers: producer can only write tag s+2 after consuming all
// tag s+1, which requires every consumer finished its tag-s pull -> no
// overwrite hazard. init kernel zeroes tags each call (poisoned ws /
// graph replay safety).
//
// MAC: split-bf16 MFMA with Wh slice in LDS (R7, proven: immune to
// regalloc + cache invalidation).

#define BATCH 128
#define SEQ   1024
#define DIN   512
#define HID   512

#define NG  8    // batch groups
#define NC  16   // col groups
#define RPB 16   // rows per block
#define CPB 32   // cols per block

typedef float v2f __attribute__((ext_vector_type(2)));
typedef __attribute__((ext_vector_type(8))) short bf16x8;
typedef __attribute__((ext_vector_type(4))) float f32x4;

// ---------------------------------------------------------------------------
// Kernel 1: xp[s][b][j] = sum_d x[b][s][d] * Wx[d][j] + bias[j]   (unchanged)
// ---------------------------------------------------------------------------
__global__ __launch_bounds__(256) void xp_gemm(
    const float* __restrict__ x, const float* __restrict__ Wx,
    const float* __restrict__ bias, float* __restrict__ xp,
    int s0)
{
    __shared__ __align__(16) float As[16][64 + 4];
    __shared__ __align__(16) float Bs[16][64];

    const int tid = threadIdx.x;
    const int tx = tid & 15;
    const int ty = tid >> 4;
    const int rowBase = blockIdx.x * 64;
    const int colBase = blockIdx.y * 64;

    const int a_r  = tid >> 2;
    const int a_k4 = (tid & 3) * 4;
    const int rr   = rowBase + a_r;
    const int s    = s0 + (rr >> 7);
    const int bb   = rr & 127;
    const float* a_row = x + ((size_t)bb * SEQ + s) * DIN;

    const int b_kk = tid >> 4;
    const int b_j4 = (tid & 15) * 4;

    v2f C[4][2] = {};

    for (int k0 = 0; k0 < DIN; k0 += 16) {
        float4 av = *reinterpret_cast<const float4*>(a_row + k0 + a_k4);
        As[a_k4 + 0][a_r] = av.x;
        As[a_k4 + 1][a_r] = av.y;
        As[a_k4 + 2][a_r] = av.z;
        As[a_k4 + 3][a_r] = av.w;
        float4 bv = *reinterpret_cast<const float4*>(Wx + (size_t)(k0 + b_kk) * HID + colBase + b_j4);
        *reinterpret_cast<float4*>(&Bs[b_kk][b_j4]) = bv;
        __syncthreads();

        #pragma unroll
        for (int kk = 0; kk < 16; ++kk) {
            float4 a4 = *reinterpret_cast<const float4*>(&As[kk][ty * 4]);
            float4 b4 = *reinterpret_cast<const float4*>(&Bs[kk][tx * 4]);
            v2f b01 = {b4.x, b4.y};
            v2f b23 = {b4.z, b4.w};
            float a[4] = {a4.x, a4.y, a4.z, a4.w};
            #pragma unroll
            for (int i = 0; i < 4; ++i) {
                C[i][0] += b01 * a[i];
                C[i][1] += b23 * a[i];
            }
        }
        __syncthreads();
    }

    float4 bias4 = *reinterpret_cast<const float4*>(bias + colBase + tx * 4);
    #pragma unroll
    for (int i = 0; i < 4; ++i) {
        int orow = rowBase + ty * 4 + i;
        float4 o;
        o.x = C[i][0].x + bias4.x;
        o.y = C[i][0].y + bias4.y;
        o.z = C[i][1].x + bias4.z;
        o.w = C[i][1].y + bias4.w;
        *reinterpret_cast<float4*>(xp + (size_t)orow * HID + colBase + tx * 4) = o;
    }
}

// ---------------------------------------------------------------------------
// Clear all exchange tags (ws is re-poisoned each call; stale/poison tags
// would be false-ready). 2*NG*RPB*HID = 131072 u64 -> 256 blocks x 512 thr.
// ---------------------------------------------------------------------------
__global__ __launch_bounds__(512) void init_hx(unsigned long long* hxT)
{
    size_t i = (size_t)blockIdx.x * 512 + threadIdx.x;
    hxT[i] = 0ull;
}

// ---------------------------------------------------------------------------
// Kernel 2: column-split recurrence, MFMA split-bf16, tagged-u64 exchange.
//   Block (cb, bb): rows [16bb, 16bb+16), cols [32cb, 32cb+32).
//   Waves: wv = tid>>6; ct = wv&1 (col 16-tile), kq = wv>>1 (128-k quarter).
//   part[kq][ct][16][16] reduced by thread (rr=tid>>5, cc=tid&31).
//
//   LDS planes (bf16, XOR-swizzled: sidx = row*512 + (k ^ ((row&7)<<3))):
//     h_hi/h_lo  [16][512]  - rebuilt from pulled tagged u64 every step
//     wT_hi/wT_lo[32][512]  - Wh slice transposed, built once per dispatch
//
//   hxT exchange: u64 = {tag(hi32) = step of the h it carries,
//                        packed(lo32) = bf16hi<<16 | bf16lo}
//   layout [buf = step&1][bb][r*HID + k]. Relaxed agent atomics only.
// ---------------------------------------------------------------------------
__global__ __launch_bounds__(512) void recur_kernel(
    const float* __restrict__ xp,             // chunk base: xp[s-s0][b][j]
    const float* __restrict__ Wh,
    float* __restrict__ out,
    unsigned long long* __restrict__ hxT,     // [2][NG][RPB*HID]
    int s0, int steps)
{
    const int bb = blockIdx.x & 7;
    const int cb = blockIdx.x >> 3;

    const int tid  = threadIdx.x;
    const int lane = tid & 63;
    const int wv   = tid >> 6;
    const int ct   = wv & 1;
    const int kq   = wv >> 1;

    const int rr = tid >> 5;    // reduce: row 0..15
    const int cc = tid & 31;    // reduce: col 0..31

    __shared__ __align__(16) short h_hi[RPB * HID];
    __shared__ __align__(16) short h_lo[RPB * HID];
    __shared__ __align__(16) short wT_hi[CPB * HID];
    __shared__ __align__(16) short wT_lo[CPB * HID];
    __shared__ __align__(16) float part[4][2][16][16];

    // ---- build split-bf16 Wh^T slice in LDS, once per dispatch.
    {
        const int cj = tid & 31;
        const int kk = tid >> 5;
        for (int i = 0; i < 32; ++i) {
            int k = i * 16 + kk;
            float w = Wh[(size_t)k * HID + CPB * cb + cj];
            unsigned int u = __float_as_uint(w);
            short hi = (short)(u >> 16);
            float r = w - __uint_as_float(u & 0xFFFF0000u);
            short lo = (short)(__float_as_uint(r) >> 16);
            int sidx = cj * HID + (k ^ ((cj & 7) << 3));
            wT_hi[sidx] = hi;
            wT_lo[sidx] = lo;
        }
    }

    // MFMA fragment addressing (loop-invariant)
    const int frow = lane & 15;             // A-row / B-col / D-col
    const int fk8  = (lane >> 4) * 8;       // k offset of this lane's 8 elems
    const int xm_a = (frow & 7) << 3;
    const int fcol = ct * 16 + frow;
    const int xm_b = (fcol & 7) << 3;
    const int a_base = frow * HID;
    const int b_base = fcol * HID;

    const int send = s0 + steps;
    for (int s = s0; s < send; ++s) {
        // prefetch xp for this step (consumed at reduce time)
        float xpv = xp[((size_t)(s - s0) * BATCH + (RPB * bb + rr)) * HID + CPB * cb + cc];

        // ---- obtain h_s into the swizzled LDS planes
        if (s == 0) {
            #pragma unroll
            for (int i = 0; i < RPB; ++i) {
                int sidx = i * HID + (tid ^ ((i & 7) << 3));
                h_hi[sidx] = 0;
                h_lo[sidx] = 0;
            }
        } else {
            const unsigned long long* src =
                hxT + ((size_t)(s & 1) * NG + bb) * (RPB * HID);
            unsigned long long v[RPB];
            // issue all 16 loads (independent -> pipelined)
            #pragma unroll
            for (int i = 0; i < RPB; ++i)
                v[i] = __hip_atomic_load(&src[i * HID + tid], __ATOMIC_RELAXED,
                                         __HIP_MEMORY_SCOPE_AGENT);
            // re-poll stragglers until their tag == s
            #pragma unroll
            for (int i = 0; i < RPB; ++i)
                while ((unsigned)(v[i] >> 32) != (unsigned)s)
                    v[i] = __hip_atomic_load(&src[i * HID + tid], __ATOMIC_RELAXED,
                                             __HIP_MEMORY_SCOPE_AGENT);
            #pragma unroll
            for (int i = 0; i < RPB; ++i) {
                unsigned int u = (unsigned int)v[i];
                int sidx = i * HID + (tid ^ ((i & 7) << 3));
                h_hi[sidx] = (short)(u >> 16);
                h_lo[sidx] = (short)(u & 0xFFFFu);
            }
        }
        __syncthreads();   // bar1: h planes ready

        // ---- MFMA phase: wave (ct,kq) computes 16x16 over its 128-k quarter
        f32x4 acc = {0.f, 0.f, 0.f, 0.f};
        #pragma unroll
        for (int kt = 0; kt < 4; ++kt) {
            int kb = kq * 128 + kt * 32 + fk8;
            bf16x8 ah = *reinterpret_cast<const bf16x8*>(&h_hi[a_base + (kb ^ xm_a)]);
            bf16x8 al = *reinterpret_cast<const bf16x8*>(&h_lo[a_base + (kb ^ xm_a)]);
            bf16x8 bh = *reinterpret_cast<const bf16x8*>(&wT_hi[b_base + (kb ^ xm_b)]);
            bf16x8 bl = *reinterpret_cast<const bf16x8*>(&wT_lo[b_base + (kb ^ xm_b)]);
            acc = __builtin_amdgcn_mfma_f32_16x16x32_bf16(ah, bh, acc, 0, 0, 0);
            acc = __builtin_amdgcn_mfma_f32_16x16x32_bf16(ah, bl, acc, 0, 0, 0);
            acc = __builtin_amdgcn_mfma_f32_16x16x32_bf16(al, bh, acc, 0, 0, 0);
            acc = __builtin_amdgcn_mfma_f32_16x16x32_bf16(al, bl, acc, 0, 0, 0);
        }

        // ---- store partials: D mapping col=lane&15, row=(lane>>4)*4+j (m89)
        #pragma unroll
        for (int j = 0; j < 4; ++j)
            part[kq][ct][(lane >> 4) * 4 + j][lane & 15] = acc[j];
        __syncthreads();   // bar2: part ready; also fences h-plane rewrite
                           // (next pull writes h only after this barrier)

        // ---- reduce 4 k-quarters, add xp, tanh
        float sum = xpv;
        #pragma unroll
        for (int g = 0; g < 4; ++g)
            sum += part[g][cc >> 4][rr][cc & 15];
        float hn = tanhf(sum);

        // ---- pack split-bf16 + tag, publish as ONE relaxed 8B agent atomic
        unsigned int uh = __float_as_uint(hn);
        float rres = hn - __uint_as_float(uh & 0xFFFF0000u);
        unsigned int packed = (uh & 0xFFFF0000u) | (__float_as_uint(rres) >> 16);
        unsigned long long val =
            ((unsigned long long)(unsigned)(s + 1) << 32) | (unsigned long long)packed;

        unsigned long long* dst =
            hxT + ((size_t)((s + 1) & 1) * NG + bb) * (RPB * HID);
        __hip_atomic_store(&dst[rr * HID + CPB * cb + cc], val,
                           __ATOMIC_RELAXED, __HIP_MEMORY_SCOPE_AGENT);
        if (s == SEQ - 1)
            out[(size_t)(RPB * bb + rr) * HID + CPB * cb + cc] = hn;
        // no trailing barrier: consumers gate on the embedded tag; LDS reuse
        // is protected by bar2 (part) and bar1 (h planes) of the next step.
    }
}

// ---------------------------------------------------------------------------
// Fallback (ws too small): fully fused, zero workspace.
// ---------------------------------------------------------------------------
__global__ __launch_bounds__(512) void fused_kernel(
    const float* __restrict__ x, const float* __restrict__ Wx,
    const float* __restrict__ Wh, const float* __restrict__ bias,
    float* __restrict__ out)
{
    __shared__ __align__(16) float h0[HID];
    __shared__ __align__(16) float h1[HID];
    __shared__ __align__(16) float x0[DIN];
    __shared__ __align__(16) float x1[DIN];

    const int j = threadIdx.x;
    const int b0 = blockIdx.x * 2;
    const int b1 = b0 + 1;

    h0[j] = 0.0f;
    h1[j] = 0.0f;
    __syncthreads();

    const float4* h04 = reinterpret_cast<const float4*>(h0);
    const float4* h14 = reinterpret_cast<const float4*>(h1);
    const float4* x04 = reinterpret_cast<const float4*>(x0);
    const float4* x14 = reinterpret_cast<const float4*>(x1);

    for (int s = 0; s < SEQ; ++s) {
        x0[j] = x[((size_t)b0 * SEQ + s) * DIN + j];
        x1[j] = x[((size_t)b1 * SEQ + s) * DIN + j];
        __syncthreads();

        float acc0 = bias[j];
        float acc1 = bias[j];
        const float* wx = Wx + j;
        const float* wh = Wh + j;
        #pragma unroll 2
        for (int k4 = 0; k4 < HID / 4; ++k4) {
            float4 hv0 = h04[k4];
            float4 hv1 = h14[k4];
            float4 xv0 = x04[k4];
            float4 xv1 = x14[k4];
            int k = k4 * 4;
            #pragma unroll
            for (int u = 0; u < 4; ++u) {
                float wxv = wx[(size_t)(k + u) * HID];
                float whv = wh[(size_t)(k + u) * HID];
                float he0 = (u == 0) ? hv0.x : (u == 1) ? hv0.y : (u == 2) ? hv0.z : hv0.w;
                float he1 = (u == 0) ? hv1.x : (u == 1) ? hv1.y : (u == 2) ? hv1.z : hv1.w;
                float xe0 = (u == 0) ? xv0.x : (u == 1) ? xv0.y : (u == 2) ? xv0.z : xv0.w;
                float xe1 = (u == 0) ? xv1.x : (u == 1) ? xv1.y : (u == 2) ? xv1.z : xv1.w;
                acc0 += xe0 * wxv + he0 * whv;
                acc1 += xe1 * wxv + he1 * whv;
            }
        }

        float n0 = tanhf(acc0);
        float n1 = tanhf(acc1);
        __syncthreads();
        h0[j] = n0;
        h1[j] = n1;
        __syncthreads();
    }

    out[(size_t)b0 * HID + j] = h0[j];
    out[(size_t)b1 * HID + j] = h1[j];
}

// ---------------------------------------------------------------------------
extern "C" void kernel_launch(void* const* d_in, const int* in_sizes, int n_in,
                              void* d_out, int out_size, void* d_ws, size_t ws_size,
                              hipStream_t stream)
{
    const float* x    = (const float*)d_in[0];  // (128, 1024, 512)
    const float* Wx   = (const float*)d_in[1];  // (512, 512)
    const float* Wh   = (const float*)d_in[2];  // (512, 512)
    const float* bias = (const float*)d_in[3];  // (512,)
    float* out = (float*)d_out;                 // (128, 512)

    const int    hxElems = 2 * NG * (RPB * HID);                      // 131072
    const size_t hxBytes = (size_t)hxElems * sizeof(unsigned long long); // 1 MB
    const size_t stepBytes = (size_t)BATCH * HID * sizeof(float);     // 256 KB
    const size_t fixed = hxBytes;

    size_t xpCapSteps = (ws_size > fixed) ? (ws_size - fixed) / stepBytes : 0;

    if (xpCapSteps >= 1) {
        unsigned long long* hxT = (unsigned long long*)d_ws;
        float* xp = (float*)((char*)d_ws + fixed);

        init_hx<<<hxElems / 512, 512, 0, stream>>>(hxT);

        int chunk = (int)((xpCapSteps < (size_t)SEQ) ? xpCapSteps : (size_t)SEQ);
        int s0 = 0;
        while (s0 < SEQ) {
            int steps = (SEQ - s0 < chunk) ? (SEQ - s0) : chunk;
            dim3 ggrid((unsigned)(steps * BATCH / 64), HID / 64);
            xp_gemm<<<ggrid, 256, 0, stream>>>(x, Wx, bias, xp, s0);
            recur_kernel<<<NG * NC, 512, 0, stream>>>(xp, Wh, out, hxT,
                                                      s0, steps);
            s0 += steps;
        }
    } else {
        fused_kernel<<<BATCH / 2, HID, 0, stream>>>(x, Wx, Wh, bias, out);
    }
}

// Round 8
// 4998.874 us; speedup vs baseline: 3.1411x; 1.1441x over previous
//
#include <hip/hip_runtime.h>
#include <hip/hip_bf16.h>

// Problem: BATCH=128, SEQ=1024, DIN=512, HID=512 (all fp32)
// out = final hidden state (128, 512) of h_t = tanh(x_t@Wx + h_{t-1}@Wh + b)
//
// R9 (from R8): R8's tagged-u64 exchange worked (7950 -> 4600us) but the
// straggler re-poll was a per-element `while` chain: with all 16 tags stale
// at step start (blocks publish in lockstep), each element costs one FULL
// serial LLC/HBM round trip -> ~16 RT/step ~= the whole 4.5us/step.
// R9 batches the re-poll into rounds: check all 16 tags, reload ALL stale
// entries together (independent loads pipeline), repeat. ~1 RT per round,
// ~1-2 rounds expected. Everything else identical to R8.
//
// MAC: split-bf16 MFMA, Wh slice in LDS (R7). Exchange: self-tagged u64
// {tag=step, packed split-bf16}, relaxed agent atomics, ping-pong buffers
// (two-deep dependency chain makes overwrite-before-read impossible).

#define BATCH 128
#define SEQ   1024
#define DIN   512
#define HID   512

#define NG  8    // batch groups
#define NC  16   // col groups
#define RPB 16   // rows per block
#define CPB 32   // cols per block

typedef float v2f __attribute__((ext_vector_type(2)));
typedef __attribute__((ext_vector_type(8))) short bf16x8;
typedef __attribute__((ext_vector_type(4))) float f32x4;

// ---------------------------------------------------------------------------
// Kernel 1: xp[s][b][j] = sum_d x[b][s][d] * Wx[d][j] + bias[j]   (unchanged)
// ---------------------------------------------------------------------------
__global__ __launch_bounds__(256) void xp_gemm(
    const float* __restrict__ x, const float* __restrict__ Wx,
    const float* __restrict__ bias, float* __restrict__ xp,
    int s0)
{
    __shared__ __align__(16) float As[16][64 + 4];
    __shared__ __align__(16) float Bs[16][64];

    const int tid = threadIdx.x;
    const int tx = tid & 15;
    const int ty = tid >> 4;
    const int rowBase = blockIdx.x * 64;
    const int colBase = blockIdx.y * 64;

    const int a_r  = tid >> 2;
    const int a_k4 = (tid & 3) * 4;
    const int rr   = rowBase + a_r;
    const int s    = s0 + (rr >> 7);
    const int bb   = rr & 127;
    const float* a_row = x + ((size_t)bb * SEQ + s) * DIN;

    const int b_kk = tid >> 4;
    const int b_j4 = (tid & 15) * 4;

    v2f C[4][2] = {};

    for (int k0 = 0; k0 < DIN; k0 += 16) {
        float4 av = *reinterpret_cast<const float4*>(a_row + k0 + a_k4);
        As[a_k4 + 0][a_r] = av.x;
        As[a_k4 + 1][a_r] = av.y;
        As[a_k4 + 2][a_r] = av.z;
        As[a_k4 + 3][a_r] = av.w;
        float4 bv = *reinterpret_cast<const float4*>(Wx + (size_t)(k0 + b_kk) * HID + colBase + b_j4);
        *reinterpret_cast<float4*>(&Bs[b_kk][b_j4]) = bv;
        __syncthreads();

        #pragma unroll
        for (int kk = 0; kk < 16; ++kk) {
            float4 a4 = *reinterpret_cast<const float4*>(&As[kk][ty * 4]);
            float4 b4 = *reinterpret_cast<const float4*>(&Bs[kk][tx * 4]);
            v2f b01 = {b4.x, b4.y};
            v2f b23 = {b4.z, b4.w};
            float a[4] = {a4.x, a4.y, a4.z, a4.w};
            #pragma unroll
            for (int i = 0; i < 4; ++i) {
                C[i][0] += b01 * a[i];
                C[i][1] += b23 * a[i];
            }
        }
        __syncthreads();
    }

    float4 bias4 = *reinterpret_cast<const float4*>(bias + colBase + tx * 4);
    #pragma unroll
    for (int i = 0; i < 4; ++i) {
        int orow = rowBase + ty * 4 + i;
        float4 o;
        o.x = C[i][0].x + bias4.x;
        o.y = C[i][0].y + bias4.y;
        o.z = C[i][1].x + bias4.z;
        o.w = C[i][1].y + bias4.w;
        *reinterpret_cast<float4*>(xp + (size_t)orow * HID + colBase + tx * 4) = o;
    }
}

// ---------------------------------------------------------------------------
// Clear all exchange tags (ws is re-poisoned each call; stale/poison tags
// would be false-ready). 2*NG*RPB*HID = 131072 u64 -> 256 blocks x 512 thr.
// ---------------------------------------------------------------------------
__global__ __launch_bounds__(512) void init_hx(unsigned long long* hxT)
{
    size_t i = (size_t)blockIdx.x * 512 + threadIdx.x;
    hxT[i] = 0ull;
}

// ---------------------------------------------------------------------------
// Kernel 2: column-split recurrence, MFMA split-bf16, tagged-u64 exchange.
//   Block (cb, bb): rows [16bb, 16bb+16), cols [32cb, 32cb+32).
//   Waves: wv = tid>>6; ct = wv&1 (col 16-tile), kq = wv>>1 (128-k quarter).
//   part[kq][ct][16][16] reduced by thread (rr=tid>>5, cc=tid&31).
//
//   LDS planes (bf16, XOR-swizzled: sidx = row*512 + (k ^ ((row&7)<<3))):
//     h_hi/h_lo  [16][512]  - rebuilt from pulled tagged u64 every step
//     wT_hi/wT_lo[32][512]  - Wh slice transposed, built once per dispatch
//
//   hxT exchange: u64 = {tag(hi32) = step of the h it carries,
//                        packed(lo32) = bf16hi<<16 | bf16lo}
//   layout [buf = step&1][bb][r*HID + k]. Relaxed agent atomics only.
// ---------------------------------------------------------------------------
__global__ __launch_bounds__(512) void recur_kernel(
    const float* __restrict__ xp,             // chunk base: xp[s-s0][b][j]
    const float* __restrict__ Wh,
    float* __restrict__ out,
    unsigned long long* __restrict__ hxT,     // [2][NG][RPB*HID]
    int s0, int steps)
{
    const int bb = blockIdx.x & 7;
    const int cb = blockIdx.x >> 3;

    const int tid  = threadIdx.x;
    const int lane = tid & 63;
    const int wv   = tid >> 6;
    const int ct   = wv & 1;
    const int kq   = wv >> 1;

    const int rr = tid >> 5;    // reduce: row 0..15
    const int cc = tid & 31;    // reduce: col 0..31

    __shared__ __align__(16) short h_hi[RPB * HID];
    __shared__ __align__(16) short h_lo[RPB * HID];
    __shared__ __align__(16) short wT_hi[CPB * HID];
    __shared__ __align__(16) short wT_lo[CPB * HID];
    __shared__ __align__(16) float part[4][2][16][16];

    // ---- build split-bf16 Wh^T slice in LDS, once per dispatch.
    {
        const int cj = tid & 31;
        const int kk = tid >> 5;
        for (int i = 0; i < 32; ++i) {
            int k = i * 16 + kk;
            float w = Wh[(size_t)k * HID + CPB * cb + cj];
            unsigned int u = __float_as_uint(w);
            short hi = (short)(u >> 16);
            float r = w - __uint_as_float(u & 0xFFFF0000u);
            short lo = (short)(__float_as_uint(r) >> 16);
            int sidx = cj * HID + (k ^ ((cj & 7) << 3));
            wT_hi[sidx] = hi;
            wT_lo[sidx] = lo;
        }
    }

    // MFMA fragment addressing (loop-invariant)
    const int frow = lane & 15;             // A-row / B-col / D-col
    const int fk8  = (lane >> 4) * 8;       // k offset of this lane's 8 elems
    const int xm_a = (frow & 7) << 3;
    const int fcol = ct * 16 + frow;
    const int xm_b = (fcol & 7) << 3;
    const int a_base = frow * HID;
    const int b_base = fcol * HID;

    const int send = s0 + steps;
    for (int s = s0; s < send; ++s) {
        // prefetch xp for this step (consumed at reduce time)
        float xpv = xp[((size_t)(s - s0) * BATCH + (RPB * bb + rr)) * HID + CPB * cb + cc];

        // ---- obtain h_s into the swizzled LDS planes
        if (s == 0) {
            #pragma unroll
            for (int i = 0; i < RPB; ++i) {
                int sidx = i * HID + (tid ^ ((i & 7) << 3));
                h_hi[sidx] = 0;
                h_lo[sidx] = 0;
            }
        } else {
            const unsigned long long* src =
                hxT + ((size_t)(s & 1) * NG + bb) * (RPB * HID);
            unsigned long long v[RPB];
            // issue all 16 loads (independent -> pipelined)
            #pragma unroll
            for (int i = 0; i < RPB; ++i)
                v[i] = __hip_atomic_load(&src[i * HID + tid], __ATOMIC_RELAXED,
                                         __HIP_MEMORY_SCOPE_AGENT);
            // batched re-poll: reload ALL stale entries per round (the loads
            // of one round are independent -> ~1 LLC/HBM RT per round), vs
            // R8's per-element spin (16 serial RTs when all tags stale).
            for (;;) {
                unsigned stale = 0u;
                #pragma unroll
                for (int i = 0; i < RPB; ++i)
                    stale |= ((unsigned)(v[i] >> 32) != (unsigned)s) ? (1u << i) : 0u;
                if (stale == 0u) break;
                #pragma unroll
                for (int i = 0; i < RPB; ++i)
                    if (stale & (1u << i))
                        v[i] = __hip_atomic_load(&src[i * HID + tid], __ATOMIC_RELAXED,
                                                 __HIP_MEMORY_SCOPE_AGENT);
            }
            #pragma unroll
            for (int i = 0; i < RPB; ++i) {
                unsigned int u = (unsigned int)v[i];
                int sidx = i * HID + (tid ^ ((i & 7) << 3));
                h_hi[sidx] = (short)(u >> 16);
                h_lo[sidx] = (short)(u & 0xFFFFu);
            }
        }
        __syncthreads();   // bar1: h planes ready

        // ---- MFMA phase: wave (ct,kq) computes 16x16 over its 128-k quarter
        f32x4 acc = {0.f, 0.f, 0.f, 0.f};
        #pragma unroll
        for (int kt = 0; kt < 4; ++kt) {
            int kb = kq * 128 + kt * 32 + fk8;
            bf16x8 ah = *reinterpret_cast<const bf16x8*>(&h_hi[a_base + (kb ^ xm_a)]);
            bf16x8 al = *reinterpret_cast<const bf16x8*>(&h_lo[a_base + (kb ^ xm_a)]);
            bf16x8 bh = *reinterpret_cast<const bf16x8*>(&wT_hi[b_base + (kb ^ xm_b)]);
            bf16x8 bl = *reinterpret_cast<const bf16x8*>(&wT_lo[b_base + (kb ^ xm_b)]);
            acc = __builtin_amdgcn_mfma_f32_16x16x32_bf16(ah, bh, acc, 0, 0, 0);
            acc = __builtin_amdgcn_mfma_f32_16x16x32_bf16(ah, bl, acc, 0, 0, 0);
            acc = __builtin_amdgcn_mfma_f32_16x16x32_bf16(al, bh, acc, 0, 0, 0);
            acc = __builtin_amdgcn_mfma_f32_16x16x32_bf16(al, bl, acc, 0, 0, 0);
        }

        // ---- store partials: D mapping col=lane&15, row=(lane>>4)*4+j (m89)
        #pragma unroll
        for (int j = 0; j < 4; ++j)
            part[kq][ct][(lane >> 4) * 4 + j][lane & 15] = acc[j];
        __syncthreads();   // bar2: part ready; also fences h-plane rewrite
                           // (next pull writes h only after this barrier)

        // ---- reduce 4 k-quarters, add xp, tanh
        float sum = xpv;
        #pragma unroll
        for (int g = 0; g < 4; ++g)
            sum += part[g][cc >> 4][rr][cc & 15];
        float hn = tanhf(sum);

        // ---- pack split-bf16 + tag, publish as ONE relaxed 8B agent atomic
        unsigned int uh = __float_as_uint(hn);
        float rres = hn - __uint_as_float(uh & 0xFFFF0000u);
        unsigned int packed = (uh & 0xFFFF0000u) | (__float_as_uint(rres) >> 16);
        unsigned long long val =
            ((unsigned long long)(unsigned)(s + 1) << 32) | (unsigned long long)packed;

        unsigned long long* dst =
            hxT + ((size_t)((s + 1) & 1) * NG + bb) * (RPB * HID);
        __hip_atomic_store(&dst[rr * HID + CPB * cb + cc], val,
                           __ATOMIC_RELAXED, __HIP_MEMORY_SCOPE_AGENT);
        if (s == SEQ - 1)
            out[(size_t)(RPB * bb + rr) * HID + CPB * cb + cc] = hn;
        // no trailing barrier: consumers gate on the embedded tag; LDS reuse
        // is protected by bar2 (part) and bar1 (h planes) of the next step.
    }
}

// ---------------------------------------------------------------------------
// Fallback (ws too small): fully fused, zero workspace.
// ---------------------------------------------------------------------------
__global__ __launch_bounds__(512) void fused_kernel(
    const float* __restrict__ x, const float* __restrict__ Wx,
    const float* __restrict__ Wh, const float* __restrict__ bias,
    float* __restrict__ out)
{
    __shared__ __align__(16) float h0[HID];
    __shared__ __align__(16) float h1[HID];
    __shared__ __align__(16) float x0[DIN];
    __shared__ __align__(16) float x1[DIN];

    const int j = threadIdx.x;
    const int b0 = blockIdx.x * 2;
    const int b1 = b0 + 1;

    h0[j] = 0.0f;
    h1[j] = 0.0f;
    __syncthreads();

    const float4* h04 = reinterpret_cast<const float4*>(h0);
    const float4* h14 = reinterpret_cast<const float4*>(h1);
    const float4* x04 = reinterpret_cast<const float4*>(x0);
    const float4* x14 = reinterpret_cast<const float4*>(x1);

    for (int s = 0; s < SEQ; ++s) {
        x0[j] = x[((size_t)b0 * SEQ + s) * DIN + j];
        x1[j] = x[((size_t)b1 * SEQ + s) * DIN + j];
        __syncthreads();

        float acc0 = bias[j];
        float acc1 = bias[j];
        const float* wx = Wx + j;
        const float* wh = Wh + j;
        #pragma unroll 2
        for (int k4 = 0; k4 < HID / 4; ++k4) {
            float4 hv0 = h04[k4];
            float4 hv1 = h14[k4];
            float4 xv0 = x04[k4];
            float4 xv1 = x14[k4];
            int k = k4 * 4;
            #pragma unroll
            for (int u = 0; u < 4; ++u) {
                float wxv = wx[(size_t)(k + u) * HID];
                float whv = wh[(size_t)(k + u) * HID];
                float he0 = (u == 0) ? hv0.x : (u == 1) ? hv0.y : (u == 2) ? hv0.z : hv0.w;
                float he1 = (u == 0) ? hv1.x : (u == 1) ? hv1.y : (u == 2) ? hv1.z : hv1.w;
                float xe0 = (u == 0) ? xv0.x : (u == 1) ? xv0.y : (u == 2) ? xv0.z : xv0.w;
                float xe1 = (u == 0) ? xv1.x : (u == 1) ? xv1.y : (u == 2) ? xv1.z : xv1.w;
                acc0 += xe0 * wxv + he0 * whv;
                acc1 += xe1 * wxv + he1 * whv;
            }
        }

        float n0 = tanhf(acc0);
        float n1 = tanhf(acc1);
        __syncthreads();
        h0[j] = n0;
        h1[j] = n1;
        __syncthreads();
    }

    out[(size_t)b0 * HID + j] = h0[j];
    out[(size_t)b1 * HID + j] = h1[j];
}

// ---------------------------------------------------------------------------
extern "C" void kernel_launch(void* const* d_in, const int* in_sizes, int n_in,
                              void* d_out, int out_size, void* d_ws, size_t ws_size,
                              hipStream_t stream)
{
    const float* x    = (const float*)d_in[0];  // (128, 1024, 512)
    const float* Wx   = (const float*)d_in[1];  // (512, 512)
    const float* Wh   = (const float*)d_in[2];  // (512, 512)
    const float* bias = (const float*)d_in[3];  // (512,)
    float* out = (float*)d_out;                 // (128, 512)

    const int    hxElems = 2 * NG * (RPB * HID);                      // 131072
    const size_t hxBytes = (size_t)hxElems * sizeof(unsigned long long); // 1 MB
    const size_t stepBytes = (size_t)BATCH * HID * sizeof(float);     // 256 KB
    const size_t fixed = hxBytes;

    size_t xpCapSteps = (ws_size > fixed) ? (ws_size - fixed) / stepBytes : 0;

    if (xpCapSteps >= 1) {
        unsigned long long* hxT = (unsigned long long*)d_ws;
        float* xp = (float*)((char*)d_ws + fixed);

        init_hx<<<hxElems / 512, 512, 0, stream>>>(hxT);

        int chunk = (int)((xpCapSteps < (size_t)SEQ) ? xpCapSteps : (size_t)SEQ);
        int s0 = 0;
        while (s0 < SEQ) {
            int steps = (SEQ - s0 < chunk) ? (SEQ - s0) : chunk;
            dim3 ggrid((unsigned)(steps * BATCH / 64), HID / 64);
            xp_gemm<<<ggrid, 256, 0, stream>>>(x, Wx, bias, xp, s0);
            recur_kernel<<<NG * NC, 512, 0, stream>>>(xp, Wh, out, hxT,
                                                      s0, steps);
            s0 += steps;
        }
    } else {
        fused_kernel<<<BATCH / 2, HID, 0, stream>>>(x, Wx, Wh, bias, out);
    }
}